// Round 9
// baseline (152.696 us; speedup 1.0000x reference)
//
#include <hip/hip_runtime.h>
#include <math.h>

typedef _Float16 half_t;
typedef half_t half8 __attribute__((ext_vector_type(8)));
typedef __fp16 fp16x2 __attribute__((ext_vector_type(2)));   // cvt_pkrtz return type
typedef float f32x4 __attribute__((ext_vector_type(4)));
typedef float f32x2 __attribute__((ext_vector_type(2)));     // -> v_pk_*_f32 (VOP3P)

#define PI_F 3.14159265358979323846f

__device__ __forceinline__ f32x2 splat2(float s) { return f32x2{s, s}; }
__device__ __forceinline__ f32x2 fma2(f32x2 a, f32x2 b, f32x2 c) {
    return __builtin_elementwise_fma(a, b, c);
}

// Fast tanh (packed pair): (e^{2z}-1) * rcp(e^{2z}+1). Scalar TRANS ops, packed rest.
__device__ __forceinline__ f32x2 ftanh2(f32x2 z) {
    z = __builtin_elementwise_min(__builtin_elementwise_max(z, splat2(-15.f)), splat2(15.f));
    f32x2 t;
    t[0] = __expf(2.f * z[0]);
    t[1] = __expf(2.f * z[1]);
    f32x2 r;
    r[0] = __builtin_amdgcn_rcpf(t[0] + 1.f);
    r[1] = __builtin_amdgcn_rcpf(t[1] + 1.f);
    return (t - splat2(1.f)) * r;
}

// XOR-swizzled J[192][64] (halves): idx(m,col) = m*64 + (((col>>3)^(m&7))<<3) + (col&7).
// Reads (m = mt*16+i):  m&7 = i&7  -> base lane-constant, mt stride = 1024 halves.
// Writes (m = c*16+p):  m&7 = p&7  -> base r-constant,    c  stride = 1024 halves.
// All ds ops = base + compile-time offset; conflict-free (R6: SQ_LDS_BANK_CONFLICT = 0).

// NOTE: no occupancy arg in launch_bounds (R4: (512,6) caused acc[] spill, 2.2GB scratch).
__global__ __launch_bounds__(256) void pinn_main(
    const float* __restrict__ pts,
    const float* __restrict__ W1, const float* __restrict__ b1,
    const float* __restrict__ b2, const float* __restrict__ b3,
    const half_t* __restrict__ wsH,    // Wt2 @0, Wt3 @4096, Wo @8192 (half idx)
    float* __restrict__ partial)
{
    __shared__ __align__(16) half_t J[192 * 64];   // 24 KB
    __shared__ float ubuf[12][16];                 // u[c][p] stage for residual

    const int tid = threadIdx.x;
    const int l   = tid & 63;
    const int w   = tid >> 6;       // wave 0..3 = output-neuron N-tile
    const int q   = l >> 4;
    const int i   = l & 15;
    const int j   = w * 16 + i;     // neuron column owned

    // loop-invariant LDS bases (halves)
    const int rb0 = i * 64 + ((q ^ (i & 7)) << 3);         // A-frag, k-chunk q*8
    const int rb1 = i * 64 + (((4 + q) ^ (i & 7)) << 3);   // A-frag, k-chunk 32+q*8

    // pass-invariant weights/biases hoisted to registers
    const half8 w2a = *(const half8*)(wsH + j * 64 + q * 8);
    const half8 w2b = *(const half8*)(wsH + j * 64 + 32 + q * 8);
    const half8 w3a = *(const half8*)(wsH + 4096 + j * 64 + q * 8);
    const half8 w3b = *(const half8*)(wsH + 4096 + j * 64 + 32 + q * 8);
    const float bj2 = b2[j], bj3 = b3[j];
    const float w0 = W1[j], w1 = W1[64 + j], bb = b1[j];
    const float w00 = w0 * w0, w01 = w0 * w1, w11 = w1 * w1;
    const float w011 = w0 * w11, bbw = bb + w0;

    half8 wo0 = {0, 0, 0, 0, 0, 0, 0, 0};   // GEMV B col 0 = Wo
    half8 wo1 = {0, 0, 0, 0, 0, 0, 0, 0};
    if (i == 0) {
        wo0 = *(const half8*)(wsH + 8192 + q * 8);
        wo1 = *(const half8*)(wsH + 8192 + 32 + q * 8);
    }

    float bsum = 0.f;

    #pragma unroll 1
    for (int pass = 0; pass < 2; ++pass) {
        const int pbase = blockIdx.x * 32 + pass * 16;

        float px[4], pt4[4];
        #pragma unroll
        for (int r = 0; r < 4; ++r) {
            const float2 xy = *(const float2*)(pts + 2 * (pbase + q * 4 + r));
            px[r] = xy.x; pt4[r] = xy.y;
        }

        // ---------------- layer 1 (2 -> 64), packed over r-pairs ----------------
        #pragma unroll
        for (int rp = 0; rp < 2; ++rp) {
            const f32x2 X = {px[2 * rp], px[2 * rp + 1]};
            const f32x2 T = {pt4[2 * rp], pt4[2 * rp + 1]};
            f32x2 o[12];
            {   // interior jet at (x,t)
                const f32x2 zv = fma2(X, splat2(w0), fma2(T, splat2(w1), splat2(bb)));
                const f32x2 a  = ftanh2(zv);
                const f32x2 d1 = splat2(1.f) - a * a;
                const f32x2 d2 = splat2(-2.f) * a * d1;
                o[0] = a;
                o[1] = d1 * splat2(w0);
                o[2] = d1 * splat2(w1);
                o[3] = d2 * splat2(w00);
                o[4] = d2 * splat2(w01);
                o[5] = d2 * splat2(w11);
            }
            {   // boundary jet at (1,t)
                const f32x2 zv = fma2(T, splat2(w1), splat2(bbw));
                const f32x2 a  = ftanh2(zv);
                const f32x2 d1 = splat2(1.f) - a * a;
                const f32x2 d2 = splat2(-2.f) * a * d1;
                const f32x2 d3 = splat2(-2.f) * (d1 * d1 + a * d2);
                o[6]  = a;
                o[7]  = d1 * splat2(w0);
                o[8]  = d1 * splat2(w1);
                o[9]  = d2 * splat2(w01);
                o[10] = d2 * splat2(w11);
                o[11] = d3 * splat2(w011);
            }
            #pragma unroll
            for (int rr = 0; rr < 2; ++rr) {
                const int p  = q * 4 + 2 * rp + rr;
                const int wb = p * 64 + ((((j >> 3) ^ p) & 7) << 3) + (j & 7);
                #pragma unroll
                for (int cc = 0; cc < 6; ++cc) {
                    const fp16x2 hv =
                        __builtin_amdgcn_cvt_pkrtz(o[2 * cc][rr], o[2 * cc + 1][rr]);
                    J[wb + (2 * cc)     * 1024] = (half_t)hv[0];
                    J[wb + (2 * cc + 1) * 1024] = (half_t)hv[1];
                }
            }
        }

        // ---------------- hidden layer: MFMA jet-GEMM + packed compose ----------------
        auto layer_step = [&](const half8 wa, const half8 wb8, const float bj) {
            __syncthreads();   // J ready
            const f32x4 zb = {bj, bj, bj, bj};
            const f32x4 z0 = {0.f, 0.f, 0.f, 0.f};
            f32x4 acc[12];
            #pragma unroll
            for (int mt = 0; mt < 12; ++mt) {
                const half8 a0 = *(const half8*)(J + rb0 + mt * 1024);
                const half8 a1 = *(const half8*)(J + rb1 + mt * 1024);
                f32x4 z = (mt == 0 || mt == 6) ? zb : z0;   // bias folded into C-init
                z = __builtin_amdgcn_mfma_f32_16x16x32_f16(a0, wa,  z, 0, 0, 0);
                z = __builtin_amdgcn_mfma_f32_16x16x32_f16(a1, wb8, z, 0, 0, 0);
                acc[mt] = z;
            }
            __syncthreads();   // all reads of J done

            #pragma unroll
            for (int rp = 0; rp < 2; ++rp) {
                const int r0 = 2 * rp, r1 = 2 * rp + 1;
                f32x2 o[12];
                {   // interior jet
                    const f32x2 zv  = {acc[0][r0], acc[0][r1]};
                    const f32x2 zx  = {acc[1][r0], acc[1][r1]};
                    const f32x2 zt  = {acc[2][r0], acc[2][r1]};
                    const f32x2 zxx = {acc[3][r0], acc[3][r1]};
                    const f32x2 zxt = {acc[4][r0], acc[4][r1]};
                    const f32x2 ztt = {acc[5][r0], acc[5][r1]};
                    const f32x2 a  = ftanh2(zv);
                    const f32x2 d1 = splat2(1.f) - a * a;
                    const f32x2 d2 = splat2(-2.f) * a * d1;
                    o[0] = a;
                    o[1] = d1 * zx;
                    o[2] = d1 * zt;
                    o[3] = fma2(d2 * zx, zx, d1 * zxx);
                    o[4] = fma2(d2 * zx, zt, d1 * zxt);
                    o[5] = fma2(d2 * zt, zt, d1 * ztt);
                }
                {   // boundary jet
                    const f32x2 zv   = {acc[6][r0],  acc[6][r1]};
                    const f32x2 zx   = {acc[7][r0],  acc[7][r1]};
                    const f32x2 zt   = {acc[8][r0],  acc[8][r1]};
                    const f32x2 zxt  = {acc[9][r0],  acc[9][r1]};
                    const f32x2 ztt  = {acc[10][r0], acc[10][r1]};
                    const f32x2 zxtt = {acc[11][r0], acc[11][r1]};
                    const f32x2 a  = ftanh2(zv);
                    const f32x2 e1 = splat2(1.f) - a * a;
                    const f32x2 e2 = splat2(-2.f) * a * e1;
                    const f32x2 e3 = splat2(-2.f) * (e1 * e1 + a * e2);
                    o[6]  = a;
                    o[7]  = e1 * zx;
                    o[8]  = e1 * zt;
                    o[9]  = fma2(e2 * zx, zt, e1 * zxt);
                    o[10] = fma2(e2 * zt, zt, e1 * ztt);
                    o[11] = fma2(e3 * zx, zt * zt,
                             fma2(e2, fma2(splat2(2.f) * zxt, zt, zx * ztt), e1 * zxtt));
                }
                #pragma unroll
                for (int rr = 0; rr < 2; ++rr) {
                    const int p  = q * 4 + 2 * rp + rr;
                    const int wb = p * 64 + ((((j >> 3) ^ p) & 7) << 3) + (j & 7);
                    #pragma unroll
                    for (int cc = 0; cc < 6; ++cc) {
                        const fp16x2 hv =
                            __builtin_amdgcn_cvt_pkrtz(o[2 * cc][rr], o[2 * cc + 1][rr]);
                        J[wb + (2 * cc)     * 1024] = (half_t)hv[0];
                        J[wb + (2 * cc + 1) * 1024] = (half_t)hv[1];
                    }
                }
            }
        };
        layer_step(w2a, w2b, bj2);
        layer_step(w3a, w3b, bj3);
        __syncthreads();   // J3 ready

        // -------- output GEMV (Wo in B col 0), split: wave w owns mt = 3w..3w+2 --------
        {
            f32x4 u3[3];
            #pragma unroll
            for (int k3 = 0; k3 < 3; ++k3) {
                const int mt = w * 3 + k3;
                const half8 a0 = *(const half8*)(J + rb0 + mt * 1024);
                const half8 a1 = *(const half8*)(J + rb1 + mt * 1024);
                f32x4 z = {0.f, 0.f, 0.f, 0.f};
                z = __builtin_amdgcn_mfma_f32_16x16x32_f16(a0, wo0, z, 0, 0, 0);
                z = __builtin_amdgcn_mfma_f32_16x16x32_f16(a1, wo1, z, 0, 0, 0);
                u3[k3] = z;
            }
            if (i == 0) {   // col 0 lanes hold u[mt][p = q*4+r]
                #pragma unroll
                for (int k3 = 0; k3 < 3; ++k3)
                    #pragma unroll
                    for (int r = 0; r < 4; ++r)
                        ubuf[w * 3 + k3][q * 4 + r] = u3[k3][r];
            }
        }
        __syncthreads();   // ubuf ready; all J reads done

        // ---------------- residual: one lane per point ----------------
        if (tid < 16) {
            const float x = pts[2 * (pbase + tid)];
            const float t = pts[2 * (pbase + tid) + 1];
            float U[12];
            #pragma unroll
            for (int c = 0; c < 12; ++c) U[c] = ubuf[c][tid];

            const float D   = U[0] - U[6] - U[7];
            const float Dx  = U[1];
            const float Dt  = U[2] - U[8] - U[9];
            const float Dxx = U[3];
            const float Dxt = U[4];
            const float Dtt = U[5] - U[10] - U[11];

            // sin(pi t) = v_sin(t/2) [revolutions], t in [0,1]
            const float s  = __builtin_amdgcn_sinf(0.5f * t);
            const float cc = __builtin_amdgcn_cosf(0.5f * t);
            const float A  = t * t - t,  Ap = 2.f * t - 1.f;
            const float B  = x * x - x,  Bp = 2.f * x - 1.f;

            const float psi    = 2.f * x * s + A * B * D;
            const float psi_x  = 2.f * s + A * (Bp * D + B * Dx);
            const float psi_xx = A * (2.f * D + 2.f * Bp * Dx + B * Dxx);
            const float psi_xt = 2.f * PI_F * cc + Ap * (Bp * D + B * Dx)
                               + A * (Bp * Dt + B * Dxt);
            const float psi_tt = -2.f * PI_F * PI_F * x * s + 2.f * B * D
                               + 2.f * Ap * B * Dt + A * B * Dtt;

            const float forcing = s * (2.f - PI_F * PI_F * x * x
                                       + 2.f * x * x * x * s);
            float s4 = fabsf(psi_xx + 2.f * psi_xt + psi_tt + psi * psi_x - forcing);
            s4 += __shfl_xor(s4, 1, 64);
            s4 += __shfl_xor(s4, 2, 64);
            s4 += __shfl_xor(s4, 4, 64);
            s4 += __shfl_xor(s4, 8, 64);
            if (tid == 0) bsum += s4;
        }
    }

    if (tid == 0) partial[blockIdx.x] = bsum;
}

__global__ __launch_bounds__(256) void pinn_prep(
    const float* __restrict__ W2, const float* __restrict__ W3,
    const float* __restrict__ Wo, half_t* __restrict__ wsH)
{
    const int tid = threadIdx.x;
    for (int idx = tid; idx < 4096; idx += 256) {
        const int n = idx >> 6, k = idx & 63;
        wsH[idx]        = (half_t)W2[k * 64 + n];   // Wt2[n][k]
        wsH[4096 + idx] = (half_t)W3[k * 64 + n];   // Wt3[n][k]
    }
    if (tid < 64) wsH[8192 + tid] = (half_t)Wo[tid];
}

__global__ __launch_bounds__(256) void pinn_reduce(
    const float* __restrict__ partial, float* __restrict__ out,
    int nblocks, float invN)
{
    __shared__ float sd[256];
    float s = 0.f;
    for (int i = threadIdx.x; i < nblocks; i += 256) s += partial[i];
    sd[threadIdx.x] = s;
    __syncthreads();
    #pragma unroll
    for (int off = 128; off > 0; off >>= 1) {
        if (threadIdx.x < off) sd[threadIdx.x] += sd[threadIdx.x + off];
        __syncthreads();
    }
    if (threadIdx.x == 0) out[0] = sd[0] * invN;
}

extern "C" void kernel_launch(void* const* d_in, const int* in_sizes, int n_in,
                              void* d_out, int out_size, void* d_ws, size_t ws_size,
                              hipStream_t stream)
{
    const float* pts = (const float*)d_in[0];
    const float* W1  = (const float*)d_in[1];
    const float* b1  = (const float*)d_in[2];
    const float* W2  = (const float*)d_in[3];
    const float* b2  = (const float*)d_in[4];
    const float* W3  = (const float*)d_in[5];
    const float* b3  = (const float*)d_in[6];
    const float* Wo  = (const float*)d_in[7];
    // d_in[8] = bo: cancels in (u - u(1,t)) and has zero derivative.

    const int nPts    = in_sizes[0] / 2;          // 262144
    const int nBlocks = nPts / 32;                // 8192 (32 pts = 2 passes x 16)

    half_t* wsH     = (half_t*)d_ws;                      // 16,512 B of weights
    float*  partial = (float*)((char*)d_ws + 32768);      // 32 KB of partials

    pinn_prep<<<1, 256, 0, stream>>>(W2, W3, Wo, wsH);
    pinn_main<<<nBlocks, 256, 0, stream>>>(pts, W1, b1, b2, b3, wsH, partial);
    pinn_reduce<<<1, 256, 0, stream>>>(partial, (float*)d_out, nBlocks,
                                       1.f / (float)nPts);
}

// Round 10
// 128.221 us; speedup vs baseline: 1.1909x; 1.1909x over previous
//
#include <hip/hip_runtime.h>
#include <math.h>

typedef _Float16 half_t;
typedef half_t half8 __attribute__((ext_vector_type(8)));
typedef half_t half4v __attribute__((ext_vector_type(4)));
typedef __fp16 fp16x2 __attribute__((ext_vector_type(2)));   // cvt_pkrtz return type
typedef float f32x4 __attribute__((ext_vector_type(4)));
typedef float f32x2 __attribute__((ext_vector_type(2)));     // -> v_pk_*_f32

#define PI_F 3.14159265358979323846f

__device__ __forceinline__ f32x2 splat2(float s) { return f32x2{s, s}; }
__device__ __forceinline__ f32x2 fma2(f32x2 a, f32x2 b, f32x2 c) {
    return __builtin_elementwise_fma(a, b, c);
}

// Fast tanh (packed pair): (e^{2z}-1) * rcp(e^{2z}+1). Validated on-harness.
__device__ __forceinline__ f32x2 ftanh2(f32x2 z) {
    z = __builtin_elementwise_min(__builtin_elementwise_max(z, splat2(-15.f)), splat2(15.f));
    f32x2 t;
    t[0] = __expf(2.f * z[0]);
    t[1] = __expf(2.f * z[1]);
    f32x2 r;
    r[0] = __builtin_amdgcn_rcpf(t[0] + 1.f);
    r[1] = __builtin_amdgcn_rcpf(t[1] + 1.f);
    return (t - splat2(1.f)) * r;
}

// TRANSPOSED layout (R10): J^T[n = c*16 + p][k = j], XOR-swizzled:
//   halfidx(n,k) = n*64 + (((k>>3) ^ (n&7)) << 3) + (k&7)
// GEMM: Z^T = W^T · J^T  ->  mfma(A = weight frag [regs], B = J^T rows).
// Lane (i,q) of wave w gets D[j = w*16+q*4+r][n = c*16+i]: all 12 comps of
// (point p=i, 4 CONSECUTIVE neurons) -> compose writes 4 halves = 1 ds_write_b64
// at (row c*16+i, cols jb..jb+3). Writes/wave/pass: 144 b16 -> 36 b64.

// NOTE: no occupancy arg in launch_bounds (R4: (512,6) caused acc[] spill, 2.2GB scratch).
__global__ __launch_bounds__(256) void pinn_main(
    const float* __restrict__ pts,
    const float* __restrict__ W1, const float* __restrict__ b1,
    const float* __restrict__ b2, const float* __restrict__ b3,
    const half_t* __restrict__ wsH,    // Wt2 @0, Wt3 @4096, Wo @8192 (half idx)
    float* __restrict__ partial)
{
    __shared__ __align__(16) half_t J[192 * 64];   // 24 KB
    __shared__ float ubuf[12][16];                 // u[c][p] stage for residual

    const int tid = threadIdx.x;
    const int l   = tid & 63;
    const int w   = tid >> 6;       // wave = output-neuron M-tile (rows of Z^T)
    const int q   = l >> 4;
    const int i   = l & 15;         // = point p owned for compose/writes
    const int ja  = w * 16 + i;     // A-operand weight row
    const int jb  = w * 16 + q * 4; // first of 4 output-neuron cols owned

    // loop-invariant LDS bases (halves)
    const int rb0 = i * 64 + ((q ^ (i & 7)) << 3);          // B-frag, k-chunk q*8
    const int rb1 = i * 64 + (((4 + q) ^ (i & 7)) << 3);    // B-frag, k-chunk 32+q*8
    const int wbase = i * 64 + ((((w * 2 + (q >> 1)) ^ (i & 7))) << 3) + (q & 1) * 4;

    // A-operand fragments (weights, registers — pass-invariant)
    const half8 w2a = *(const half8*)(wsH + ja * 64 + q * 8);
    const half8 w2b = *(const half8*)(wsH + ja * 64 + 32 + q * 8);
    const half8 w3a = *(const half8*)(wsH + 4096 + ja * 64 + q * 8);
    const half8 w3b = *(const half8*)(wsH + 4096 + ja * 64 + 32 + q * 8);

    // per-output-neuron params: 4 contiguous -> float4 loads
    const float4 w04 = *(const float4*)(W1 + jb);
    const float4 w14 = *(const float4*)(W1 + 64 + jb);
    const float4 b14 = *(const float4*)(b1 + jb);
    const float4 b24 = *(const float4*)(b2 + jb);
    const float4 b34 = *(const float4*)(b3 + jb);

    half8 wo0 = {0, 0, 0, 0, 0, 0, 0, 0};   // GEMV A-frag: row 0 = Wo
    half8 wo1 = {0, 0, 0, 0, 0, 0, 0, 0};
    if (i == 0) {
        wo0 = *(const half8*)(wsH + 8192 + q * 8);
        wo1 = *(const half8*)(wsH + 8192 + 32 + q * 8);
    }

    // packed write: one b64 = comp c for 4 neurons (pairs 01, 23)
    auto stc = [&](int c, f32x2 v01, f32x2 v23) {
        const fp16x2 h0 = __builtin_amdgcn_cvt_pkrtz(v01[0], v01[1]);
        const fp16x2 h1 = __builtin_amdgcn_cvt_pkrtz(v23[0], v23[1]);
        const half4v v = { (half_t)h0[0], (half_t)h0[1], (half_t)h1[0], (half_t)h1[1] };
        *(half4v*)(&J[wbase + c * 1024]) = v;
    };

    // neuron-pair packed layer-1 params
    const f32x2 w0a = {w04.x, w04.y}, w0b = {w04.z, w04.w};
    const f32x2 w1a = {w14.x, w14.y}, w1b = {w14.z, w14.w};
    const f32x2 bba = {b14.x, b14.y}, bbb = {b14.z, b14.w};

    float bsum = 0.f;

    #pragma unroll 1
    for (int pass = 0; pass < 2; ++pass) {
        const int pbase = blockIdx.x * 32 + pass * 16;

        const float2 xy = *(const float2*)(pts + 2 * (pbase + i));   // point p = i
        const float X = xy.x, T = xy.y;

        // ---------------- layer 1 (2 -> 64): jets for point i, 4 neurons ----------------
        {   // interior jet at (x,t)
            const f32x2 zva = fma2(splat2(X), w0a, fma2(splat2(T), w1a, bba));
            const f32x2 zvb = fma2(splat2(X), w0b, fma2(splat2(T), w1b, bbb));
            const f32x2 aa = ftanh2(zva), ab = ftanh2(zvb);
            const f32x2 d1a = splat2(1.f) - aa * aa, d1b = splat2(1.f) - ab * ab;
            const f32x2 d2a = splat2(-2.f) * aa * d1a, d2b = splat2(-2.f) * ab * d1b;
            stc(0, aa, ab);
            stc(1, d1a * w0a, d1b * w0b);
            stc(2, d1a * w1a, d1b * w1b);
            stc(3, d2a * w0a * w0a, d2b * w0b * w0b);
            stc(4, d2a * w0a * w1a, d2b * w0b * w1b);
            stc(5, d2a * w1a * w1a, d2b * w1b * w1b);
        }
        {   // boundary jet at (1,t)
            const f32x2 zva = fma2(splat2(T), w1a, bba + w0a);
            const f32x2 zvb = fma2(splat2(T), w1b, bbb + w0b);
            const f32x2 aa = ftanh2(zva), ab = ftanh2(zvb);
            const f32x2 e1a = splat2(1.f) - aa * aa, e1b = splat2(1.f) - ab * ab;
            const f32x2 e2a = splat2(-2.f) * aa * e1a, e2b = splat2(-2.f) * ab * e1b;
            const f32x2 e3a = splat2(-2.f) * (e1a * e1a + aa * e2a);
            const f32x2 e3b = splat2(-2.f) * (e1b * e1b + ab * e2b);
            stc(6, aa, ab);
            stc(7, e1a * w0a, e1b * w0b);
            stc(8, e1a * w1a, e1b * w1b);
            stc(9, e2a * w0a * w1a, e2b * w0b * w1b);
            stc(10, e2a * w1a * w1a, e2b * w1b * w1b);
            stc(11, e3a * w0a * w1a * w1a, e3b * w0b * w1b * w1b);
        }

        // ---------------- hidden layer: MFMA jet-GEMM + packed compose ----------------
        auto layer_step = [&](const half8 A0, const half8 A1, const float4 b4) {
            __syncthreads();   // J ready
            const f32x4 zb = {b4.x, b4.y, b4.z, b4.w};
            const f32x4 z0 = {0.f, 0.f, 0.f, 0.f};
            f32x4 acc[12];
            #pragma unroll
            for (int c = 0; c < 12; ++c) {
                const half8 f0 = *(const half8*)(&J[rb0 + c * 1024]);
                const half8 f1 = *(const half8*)(&J[rb1 + c * 1024]);
                f32x4 z = (c == 0 || c == 6) ? zb : z0;   // bias folded into C-init
                z = __builtin_amdgcn_mfma_f32_16x16x32_f16(A0, f0, z, 0, 0, 0);
                z = __builtin_amdgcn_mfma_f32_16x16x32_f16(A1, f1, z, 0, 0, 0);
                acc[c] = z;
            }
            __syncthreads();   // all reads of J done

            {   // interior jet (comps 0..5), neuron pairs (01),(23)
                const f32x2 zva = {acc[0][0], acc[0][1]}, zvb = {acc[0][2], acc[0][3]};
                const f32x2 aa = ftanh2(zva), ab = ftanh2(zvb);
                const f32x2 d1a = splat2(1.f) - aa * aa, d1b = splat2(1.f) - ab * ab;
                const f32x2 d2a = splat2(-2.f) * aa * d1a, d2b = splat2(-2.f) * ab * d1b;
                const f32x2 zxa = {acc[1][0], acc[1][1]}, zxb = {acc[1][2], acc[1][3]};
                const f32x2 zta = {acc[2][0], acc[2][1]}, ztb = {acc[2][2], acc[2][3]};
                const f32x2 zxxa = {acc[3][0], acc[3][1]}, zxxb = {acc[3][2], acc[3][3]};
                const f32x2 zxta = {acc[4][0], acc[4][1]}, zxtb = {acc[4][2], acc[4][3]};
                const f32x2 ztta = {acc[5][0], acc[5][1]}, zttb = {acc[5][2], acc[5][3]};
                stc(0, aa, ab);
                stc(1, d1a * zxa, d1b * zxb);
                stc(2, d1a * zta, d1b * ztb);
                stc(3, fma2(d2a * zxa, zxa, d1a * zxxa), fma2(d2b * zxb, zxb, d1b * zxxb));
                stc(4, fma2(d2a * zxa, zta, d1a * zxta), fma2(d2b * zxb, ztb, d1b * zxtb));
                stc(5, fma2(d2a * zta, zta, d1a * ztta), fma2(d2b * ztb, ztb, d1b * zttb));
            }
            {   // boundary jet (comps 6..11)
                const f32x2 zva = {acc[6][0], acc[6][1]}, zvb = {acc[6][2], acc[6][3]};
                const f32x2 aa = ftanh2(zva), ab = ftanh2(zvb);
                const f32x2 e1a = splat2(1.f) - aa * aa, e1b = splat2(1.f) - ab * ab;
                const f32x2 e2a = splat2(-2.f) * aa * e1a, e2b = splat2(-2.f) * ab * e1b;
                const f32x2 e3a = splat2(-2.f) * (e1a * e1a + aa * e2a);
                const f32x2 e3b = splat2(-2.f) * (e1b * e1b + ab * e2b);
                const f32x2 zxa  = {acc[7][0], acc[7][1]},  zxb  = {acc[7][2], acc[7][3]};
                const f32x2 zta  = {acc[8][0], acc[8][1]},  ztb  = {acc[8][2], acc[8][3]};
                const f32x2 zxta = {acc[9][0], acc[9][1]},  zxtb = {acc[9][2], acc[9][3]};
                const f32x2 ztta = {acc[10][0], acc[10][1]}, zttb = {acc[10][2], acc[10][3]};
                const f32x2 zxtta = {acc[11][0], acc[11][1]}, zxttb = {acc[11][2], acc[11][3]};
                stc(6, aa, ab);
                stc(7, e1a * zxa, e1b * zxb);
                stc(8, e1a * zta, e1b * ztb);
                stc(9, fma2(e2a * zxa, zta, e1a * zxta), fma2(e2b * zxb, ztb, e1b * zxtb));
                stc(10, fma2(e2a * zta, zta, e1a * ztta), fma2(e2b * ztb, ztb, e1b * zttb));
                stc(11,
                    fma2(e3a * zxa, zta * zta,
                         fma2(e2a, fma2(splat2(2.f) * zxta, zta, zxa * ztta), e1a * zxtta)),
                    fma2(e3b * zxb, ztb * ztb,
                         fma2(e2b, fma2(splat2(2.f) * zxtb, ztb, zxb * zttb), e1b * zxttb)));
            }
        };
        layer_step(w2a, w2b, b24);
        layer_step(w3a, w3b, b34);
        __syncthreads();   // J3 ready

        // ---- output GEMV (Wo as A row 0), wave w owns comps c = 3w..3w+2 ----
        {
            const int rbg0 = rb0 + w * 3 * 1024;
            const int rbg1 = rb1 + w * 3 * 1024;
            #pragma unroll
            for (int k3 = 0; k3 < 3; ++k3) {
                const half8 f0 = *(const half8*)(&J[rbg0 + k3 * 1024]);
                const half8 f1 = *(const half8*)(&J[rbg1 + k3 * 1024]);
                f32x4 z = {0.f, 0.f, 0.f, 0.f};
                z = __builtin_amdgcn_mfma_f32_16x16x32_f16(wo0, f0, z, 0, 0, 0);
                z = __builtin_amdgcn_mfma_f32_16x16x32_f16(wo1, f1, z, 0, 0, 0);
                if (q == 0) ubuf[w * 3 + k3][i] = z[0];   // D row 0 -> q==0 lanes, reg 0
            }
        }
        __syncthreads();   // ubuf ready; all J reads done

        // ---------------- residual: one lane per point ----------------
        if (tid < 16) {
            // for tid<16: w=0,q=0,i=tid -> X,T are this point's coords
            const float x = X, t = T;
            float U[12];
            #pragma unroll
            for (int c = 0; c < 12; ++c) U[c] = ubuf[c][tid];

            const float D   = U[0] - U[6] - U[7];
            const float Dx  = U[1];
            const float Dt  = U[2] - U[8] - U[9];
            const float Dxx = U[3];
            const float Dxt = U[4];
            const float Dtt = U[5] - U[10] - U[11];

            // sin(pi t) = v_sin(t/2) [revolutions], t in [0,1]
            const float s  = __builtin_amdgcn_sinf(0.5f * t);
            const float cc = __builtin_amdgcn_cosf(0.5f * t);
            const float A  = t * t - t,  Ap = 2.f * t - 1.f;
            const float B  = x * x - x,  Bp = 2.f * x - 1.f;

            const float psi    = 2.f * x * s + A * B * D;
            const float psi_x  = 2.f * s + A * (Bp * D + B * Dx);
            const float psi_xx = A * (2.f * D + 2.f * Bp * Dx + B * Dxx);
            const float psi_xt = 2.f * PI_F * cc + Ap * (Bp * D + B * Dx)
                               + A * (Bp * Dt + B * Dxt);
            const float psi_tt = -2.f * PI_F * PI_F * x * s + 2.f * B * D
                               + 2.f * Ap * B * Dt + A * B * Dtt;

            const float forcing = s * (2.f - PI_F * PI_F * x * x
                                       + 2.f * x * x * x * s);
            float s4 = fabsf(psi_xx + 2.f * psi_xt + psi_tt + psi * psi_x - forcing);
            s4 += __shfl_xor(s4, 1, 64);
            s4 += __shfl_xor(s4, 2, 64);
            s4 += __shfl_xor(s4, 4, 64);
            s4 += __shfl_xor(s4, 8, 64);
            if (tid == 0) bsum += s4;
        }
        // next pass's layer-1 J writes are safe: GEMV reads completed before the
        // post-GEMV barrier; residual touches only ubuf/registers.
    }

    if (tid == 0) partial[blockIdx.x] = bsum;
}

__global__ __launch_bounds__(256) void pinn_prep(
    const float* __restrict__ W2, const float* __restrict__ W3,
    const float* __restrict__ Wo, half_t* __restrict__ wsH)
{
    const int tid = threadIdx.x;
    for (int idx = tid; idx < 4096; idx += 256) {
        const int n = idx >> 6, k = idx & 63;
        wsH[idx]        = (half_t)W2[k * 64 + n];   // Wt2[n][k]
        wsH[4096 + idx] = (half_t)W3[k * 64 + n];   // Wt3[n][k]
    }
    if (tid < 64) wsH[8192 + tid] = (half_t)Wo[tid];
}

__global__ __launch_bounds__(256) void pinn_reduce(
    const float* __restrict__ partial, float* __restrict__ out,
    int nblocks, float invN)
{
    __shared__ float sd[256];
    float s = 0.f;
    for (int i = threadIdx.x; i < nblocks; i += 256) s += partial[i];
    sd[threadIdx.x] = s;
    __syncthreads();
    #pragma unroll
    for (int off = 128; off > 0; off >>= 1) {
        if (threadIdx.x < off) sd[threadIdx.x] += sd[threadIdx.x + off];
        __syncthreads();
    }
    if (threadIdx.x == 0) out[0] = sd[0] * invN;
}

extern "C" void kernel_launch(void* const* d_in, const int* in_sizes, int n_in,
                              void* d_out, int out_size, void* d_ws, size_t ws_size,
                              hipStream_t stream)
{
    const float* pts = (const float*)d_in[0];
    const float* W1  = (const float*)d_in[1];
    const float* b1  = (const float*)d_in[2];
    const float* W2  = (const float*)d_in[3];
    const float* b2  = (const float*)d_in[4];
    const float* W3  = (const float*)d_in[5];
    const float* b3  = (const float*)d_in[6];
    const float* Wo  = (const float*)d_in[7];
    // d_in[8] = bo: cancels in (u - u(1,t)) and has zero derivative.

    const int nPts    = in_sizes[0] / 2;          // 262144
    const int nBlocks = nPts / 32;                // 8192 (32 pts = 2 passes x 16)

    half_t* wsH     = (half_t*)d_ws;                      // 16,512 B of weights
    float*  partial = (float*)((char*)d_ws + 32768);      // 32 KB of partials

    pinn_prep<<<1, 256, 0, stream>>>(W2, W3, Wo, wsH);
    pinn_main<<<nBlocks, 256, 0, stream>>>(pts, W1, b1, b2, b3, wsH, partial);
    pinn_reduce<<<1, 256, 0, stream>>>(partial, (float*)d_out, nBlocks,
                                       1.f / (float)nPts);
}